// Round 13
// baseline (232.737 us; speedup 1.0000x reference)
//
#include <hip/hip_runtime.h>
#include <math.h>

#define N_NODES 30000
#define N_EDGES 480000

typedef __attribute__((ext_vector_type(8))) short short8;
typedef __attribute__((ext_vector_type(4))) float f32x4;
typedef __attribute__((ext_vector_type(2))) float f32x2;
typedef __attribute__((ext_vector_type(4))) unsigned uint4v;

__device__ __forceinline__ unsigned short f2bf(float f) {
    unsigned u = __float_as_uint(f);
    u += 0x7fff + ((u >> 16) & 1);          // RNE
    return (unsigned short)(u >> 16);
}
__device__ __forceinline__ float bfLO(unsigned v) { return __uint_as_float(v << 16); }
__device__ __forceinline__ float bfHI(unsigned v) { return __uint_as_float(v & 0xffff0000u); }
__device__ __forceinline__ unsigned packbf(float a, float b) {
    return (unsigned)f2bf(a) | ((unsigned)f2bf(b) << 16);
}
// truncation pack (products of bf16-exact values: err <= 2^-8, no carry chain)
__device__ __forceinline__ unsigned ptk(float a, float b) {
    return (__float_as_uint(a) >> 16) | (__float_as_uint(b) & 0xffff0000u);
}

union U8 { short8 v; unsigned u[4]; };
union C4 { f32x4 v; float f[4]; };

// ---------------------------------------------------------------------------
// k_pre: blocks 0..1874 (16 nodes each): x-precompute as MFMA GEMM, with the
// CSR degree count FUSED and the rank KEPT (epos[e] = old count) -- the
// atomic pass stays hidden under the GEMM (R3/R8-measured) while making fill
// atomic-free. epos lives in d_out (dead until k_main overwrites it).
// Blocks 1875..1878: pack W matrices to MFMA order.
// ---------------------------------------------------------------------------
__global__ __launch_bounds__(256) void k_pre(
    const float* __restrict__ node_s,   // (N,32)
    const float* __restrict__ node_v,   // (N,32,3)
    const float* __restrict__ W1_0,     // (32,32) [u][w]
    const float* __restrict__ W1_1,
    const float* __restrict__ Wsc0,     // (256,32)
    const float* __restrict__ Wsc1,
    const float* __restrict__ W2_0,     // (64,32)
    const float* __restrict__ W2_1,
    const int* __restrict__ edge_src,
    int* __restrict__ deg,
    int* __restrict__ epos,             // (E) CSR rank, in d_out
    unsigned short* __restrict__ xnode, // (N,128) bf16 packed
    unsigned* __restrict__ bsc0,        // 4096 uints
    unsigned* __restrict__ bsc1,
    unsigned* __restrict__ b20,         // 1024 uints
    unsigned* __restrict__ b21)
{
    __shared__ float sVT[16 * 100];     // [nl][d*32+u]
    __shared__ float sXo[16 * 140];     // [nl][p*34+w], p=0:x0, 1+d:x1_d
    int tid = threadIdx.x;

    if (blockIdx.x >= 1875) {
        int b = blockIdx.x - 1875;
        const float* Wm = (b == 0) ? Wsc0 : (b == 1) ? Wsc1 : (b == 2) ? W2_0 : W2_1;
        unsigned* dst = (b == 0) ? bsc0 : (b == 1) ? bsc1 : (b == 2) ? b20 : b21;
        float scale = (b < 2) ? 0.0625f : 0.03125f;  // exact pow2 folds
        int nu = (b < 2) ? 4096 : 1024;
        for (int idx = tid; idx < nu; idx += 256) {
            int jp = idx & 3;
            int lane = (idx >> 2) & 63;
            int ft = (idx >> 8) & 1;
            int kc = idx >> 9;
            int quad = lane >> 4, col = lane & 15;
            int k = kc * 32 + quad * 8 + jp * 2;
            int c = ft * 16 + col;
            dst[idx] = packbf(Wm[k * 32 + c] * scale, Wm[(k + 1) * 32 + c] * scale);
        }
        return;
    }

    int e = blockIdx.x * 256 + tid;
    epos[e] = atomicAdd(&deg[edge_src[e]], 1);   // hidden under GEMM below

    int nbase = blockIdx.x * 16;
    // stage node_v transposed: sVT[nl][d*32+u]
    for (int i = tid; i < 1536; i += 256) {
        int nl = i / 96, r = i - nl * 96;
        int u = r / 3, d = r - u * 3;
        sVT[nl * 100 + d * 32 + u] = node_v[(size_t)nbase * 96 + i];
    }
    __syncthreads();

    int lane = tid & 63;
    int wv = tid >> 6;
    int col = lane & 15, quad = lane >> 4, m = lane & 15;

    // B fragments from W1 (scale applied at pack stage)
    const float* W1 = (wv == 0) ? W1_0 : W1_1;
    U8 bf0, bf1;
#pragma unroll
    for (int p = 0; p < 4; ++p) {
        int k = quad * 8 + 2 * p;
        bf0.u[p] = packbf(W1[k * 32 + col],      W1[(k + 1) * 32 + col]);
        bf1.u[p] = packbf(W1[k * 32 + col + 16], W1[(k + 1) * 32 + col + 16]);
    }

    // A fragment (K=32 covered by one MFMA)
    U8 af;
    if (wv == 0) {
        const float* sp = node_s + (size_t)(nbase + m) * 32 + quad * 8;
        float4 a0 = *(const float4*)(sp);
        float4 a1 = *(const float4*)(sp + 4);
        af.u[0] = packbf(a0.x, a0.y); af.u[1] = packbf(a0.z, a0.w);
        af.u[2] = packbf(a1.x, a1.y); af.u[3] = packbf(a1.z, a1.w);
    } else {
        int R = 16 * (wv - 1) + m;
        int nl = R / 3, d = R - nl * 3;
        const float* vp = sVT + nl * 100 + d * 32 + quad * 8;
        af.u[0] = packbf(vp[0], vp[1]); af.u[1] = packbf(vp[2], vp[3]);
        af.u[2] = packbf(vp[4], vp[5]); af.u[3] = packbf(vp[6], vp[7]);
    }

    f32x4 acc0 = {0.f, 0.f, 0.f, 0.f};
    f32x4 acc1 = {0.f, 0.f, 0.f, 0.f};
    acc0 = __builtin_amdgcn_mfma_f32_16x16x32_bf16(af.v, bf0.v, acc0, 0, 0, 0);
    acc1 = __builtin_amdgcn_mfma_f32_16x16x32_bf16(af.v, bf1.v, acc1, 0, 0, 0);

    C4 c0, c1;
    c0.v = acc0; c1.v = acc1;
    if (wv == 0) {
#pragma unroll
        for (int r = 0; r < 4; ++r) {
            int nl = (quad << 2) + r;
            sXo[nl * 140 + col]      = c0.f[r];
            sXo[nl * 140 + col + 16] = c1.f[r];
        }
    } else {
#pragma unroll
        for (int r = 0; r < 4; ++r) {
            int R = 16 * (wv - 1) + (quad << 2) + r;
            int nl = R / 3, d = R - nl * 3;
            sXo[nl * 140 + (1 + d) * 34 + col]      = c0.f[r];
            sXo[nl * 140 + (1 + d) * 34 + col + 16] = c1.f[r];
        }
    }
    __syncthreads();

    const float inv_m = 0.1767766953f;  // 1/sqrt(32)
    for (int i = tid; i < 512; i += 256) {
        int nl = i >> 5, u = i & 31;
        const float* xp = sXo + nl * 140;
        uint2 pk;
        pk.x = packbf(xp[u] * inv_m,       xp[34 + u] * inv_m);
        pk.y = packbf(xp[68 + u] * inv_m,  xp[102 + u] * inv_m);
        *(uint2*)(xnode + (size_t)(nbase + nl) * 128 + u * 4) = pk;
    }
}

// ---------------------------------------------------------------------------
// scan: single-block exclusive prefix over deg -> offs.
// ---------------------------------------------------------------------------
__global__ __launch_bounds__(1024) void scan_kernel(const int* __restrict__ deg,
                                                    int* __restrict__ offs) {
    __shared__ int sdeg[N_NODES];
    __shared__ int wsum[16];
    int tid = threadIdx.x;
#pragma unroll
    for (int k = 0; k < 30; ++k) {
        int idx = k * 1024 + tid;
        if (idx < N_NODES) sdeg[idx] = deg[idx];
    }
    __syncthreads();
    int base = tid * 30;
    int s = 0;
    if (base < N_NODES) {
#pragma unroll
        for (int k = 0; k < 30; ++k) s += sdeg[base + k];
    }
    int lane = tid & 63, wid = tid >> 6;
    int inc = s;
#pragma unroll
    for (int d = 1; d < 64; d <<= 1) {
        int o = __shfl_up(inc, d, 64);
        if (lane >= d) inc += o;
    }
    if (lane == 63) wsum[wid] = inc;
    __syncthreads();
    if (tid < 16) {
        int v = wsum[tid];
        int t = v;
#pragma unroll
        for (int d = 1; d < 16; d <<= 1) {
            int o = __shfl_up(t, d, 64);
            if (tid >= d) t += o;
        }
        wsum[tid] = t - v;
    }
    __syncthreads();
    int run = inc - s + wsum[wid];
    if (base < N_NODES) {
#pragma unroll
        for (int k = 0; k < 30; ++k) {
            int n = base + k;
            int d = sdeg[n];
            sdeg[n] = run;
            run += d;
        }
    }
    __syncthreads();
#pragma unroll
    for (int k = 0; k < 30; ++k) {
        int idx = k * 1024 + tid;
        if (idx < N_NODES) offs[idx] = sdeg[idx];
    }
    if (tid == 0) offs[N_NODES] = N_EDGES;
}

// ---------------------------------------------------------------------------
// fill: per-edge radial MLP h = ssp(es@Wfc1/sqrt(8)); writes ONE 32B record
// per edge at its CSR slot: {h[8] bf16 | ea[4] bf16, dst*256 (byte off), pad}.
// ATOMIC-FREE: pos = offs[src] + epos[e]. Record scatter uses NON-TEMPORAL
// stores: random 32B writes to distinct 128B lines cost a read-for-ownership
// each (4x write-amp, measured 61MB for 15.4MB payload in R9); nt stores
// write-combine without the ownership read. Kernel boundary guarantees
// visibility to k_main.
// ---------------------------------------------------------------------------
__global__ __launch_bounds__(256) void fill_kernel(
    const float* __restrict__ edge_attr,     // (E,4)
    const float* __restrict__ edge_scalars,  // (E,8)
    const float* __restrict__ Wfc1,          // (8,8) [k][i]
    const int* __restrict__ edge_src,
    const int* __restrict__ edge_dst,
    const int* __restrict__ offs,
    const int* __restrict__ epos,
    uint4* __restrict__ rec)                 // (E,2) uint4
{
    __shared__ float sW[64];
    int tid = threadIdx.x;
    if (tid < 64) sW[tid] = Wfc1[tid];
    __syncthreads();

    int e = blockIdx.x * 256 + tid;
    float4 es0 = *(const float4*)(edge_scalars + (size_t)e * 8);
    float4 es1 = *(const float4*)(edge_scalars + (size_t)e * 8 + 4);
    float4 ea  = *(const float4*)(edge_attr + (size_t)e * 4);
    int src = edge_src[e];
    int dst = edge_dst[e];
    int pos = offs[src] + epos[e];

    const float inv8 = 0.3535533906f;
    float h[8];
#pragma unroll
    for (int i = 0; i < 8; ++i) {
        float acc = es0.x * sW[0 * 8 + i];
        acc = fmaf(es0.y, sW[1 * 8 + i], acc);
        acc = fmaf(es0.z, sW[2 * 8 + i], acc);
        acc = fmaf(es0.w, sW[3 * 8 + i], acc);
        acc = fmaf(es1.x, sW[4 * 8 + i], acc);
        acc = fmaf(es1.y, sW[5 * 8 + i], acc);
        acc = fmaf(es1.z, sW[6 * 8 + i], acc);
        acc = fmaf(es1.w, sW[7 * 8 + i], acc);
        acc *= inv8;
        float ax = fabsf(acc);
        float tt = __expf(-ax);
        h[i] = fmaxf(acc, 0.f) + __logf(1.f + tt) - 0.6931471806f;
    }
    uint4v v0, v1;
    v0.x = packbf(h[0], h[1]); v0.y = packbf(h[2], h[3]);
    v0.z = packbf(h[4], h[5]); v0.w = packbf(h[6], h[7]);
    v1.x = packbf(ea.x, ea.y); v1.y = packbf(ea.z, ea.w);
    v1.z = ((unsigned)dst) << 8;             // xnode BYTE offset
    v1.w = 0;
    __builtin_nontemporal_store(v0, (uint4v*)(rec + 2 * pos));
    __builtin_nontemporal_store(v1, (uint4v*)(rec + 2 * pos + 1));
}

// ---------------------------------------------------------------------------
// k_main: FUSED gather + output GEMMs, 1875 blocks x 16 nodes (single
// dispatch: R6 proved half-grids collapse occupancy 45->28% VALUBusy).
// Phase 1: 4 waves x 4 sequential nodes; mov-free 6-slot rec pipeline,
//   x prefetched 4 steps ahead; Wfc2 direct from global (R5, -3us).
// Phase 2: W2 GEMM (K=64) + self-connection GEMM (K=256) via MFMA.
// ---------------------------------------------------------------------------
struct GAcc {
    float sa, sb, va2, vb2;
    f32x2 va01, vb01;
};

__device__ __forceinline__ void gstep(
    uint4& RS0, uint4& RS1, uint2& XS, const uint4& RN1, uint2& XN,
    int& t, int cntH, int& pf, int L,
    const char* recc, const char* xbc,
    const f32x2* wfA, const f32x2* wfB, GAcc& g)
{
    float hv[8];
    hv[0] = bfLO(RS0.x); hv[1] = bfHI(RS0.x);
    hv[2] = bfLO(RS0.y); hv[3] = bfHI(RS0.y);
    hv[4] = bfLO(RS0.z); hv[5] = bfHI(RS0.z);
    hv[6] = bfLO(RS0.w); hv[7] = bfHI(RS0.w);
    float sh0  = bfLO(RS1.x), s1xe = bfHI(RS1.x);
    float s1ye = bfLO(RS1.y), s1ze = bfHI(RS1.y);
    float xv0 = bfLO(XS.x), xd0 = bfHI(XS.x);
    float xd1 = bfLO(XS.y), xd2 = bfHI(XS.y);
    bool ok = (t < cntH);

    // prefetch rec[t+6] into the slot just consumed (clamped; harmless dup)
    RS0 = *(const uint4*)(recc + pf);
    RS1 = *(const uint4*)(recc + pf + 16);
    pf = min(pf + 64, L);
    // prefetch x[t+4] using rec[t+4]'s dst byte-offset
    XN = *(const uint2*)(xbc + RN1.z);

    f32x2 aA = {0.f, 0.f}, aB = {0.f, 0.f};
#pragma unroll
    for (int q = 0; q < 8; ++q) {
        f32x2 hh = {hv[q], hv[q]};
        aA = __builtin_elementwise_fma(hh, wfA[q], aA);
        aB = __builtin_elementwise_fma(hh, wfB[q], aB);
    }
    float a00 = ok ? aA.x : 0.f;
    float a01 = ok ? aA.y : 0.f;
    float a10 = ok ? aB.x : 0.f;
    float a11 = ok ? aB.y : 0.f;

    float dot = xd0 * s1xe + xd1 * s1ye + xd2 * s1ze;
    g.sa = fmaf(a00 * sh0, xv0, g.sa);
    g.sb = fmaf(a11, dot, g.sb);
    float w01x0 = a01 * xv0;
    float t10 = a10 * sh0;
    f32x2 wb = {w01x0, w01x0};
    f32x2 tb = {t10, t10};
    f32x2 s01 = {s1xe, s1ye};
    f32x2 xd01 = {xd0, xd1};
    g.va01 = __builtin_elementwise_fma(wb, s01, g.va01);
    g.vb01 = __builtin_elementwise_fma(tb, xd01, g.vb01);
    g.va2 = fmaf(w01x0, s1ze, g.va2);
    g.vb2 = fmaf(t10, xd2, g.vb2);
    ++t;
}

__global__ __launch_bounds__(256) void k_main(
    const int* __restrict__ offs,
    const uint4* __restrict__ rec,           // (E,2)
    const float* __restrict__ Wfc2,          // (8,128)
    const unsigned short* __restrict__ xnode,
    const float* __restrict__ node_s,        // (N,32)
    const float* __restrict__ node_v,        // (N,32,3)
    const float* __restrict__ node_attr,     // (N,8)
    const unsigned* __restrict__ bsc0,
    const unsigned* __restrict__ bsc1,
    const unsigned* __restrict__ b20,
    const unsigned* __restrict__ b21,
    float* __restrict__ out)                 // (N,128)
{
    __shared__ float sS[16 * 33];            // node_s staged [nl][u]
    __shared__ float sV[16 * 100];           // node_v staged [nl][u*3+d]
    __shared__ unsigned short sAgg[16 * 264];// agg rows [nl][ch], pad 8
    int tid = threadIdx.x;

    int nbase = blockIdx.x * 16;
    for (int i = tid; i < 512; i += 256)
        sS[(i >> 5) * 33 + (i & 31)] = node_s[(size_t)nbase * 32 + i];
    for (int i = tid; i < 1536; i += 256)
        sV[(i / 96) * 100 + (i % 96)] = node_v[(size_t)nbase * 96 + i];
    // no barrier needed: sS/sV first read after the phase-2 barrier

    int lane = tid & 63;
    int u = lane & 31;
    int half = lane >> 5;
    int wv = tid >> 6;

    // ---- phase 1: 4 sequential nodes per wave ----
    const float inv8 = 0.3535533906f;
    const float i8s3 = 0.3535533906f * 0.5773502692f;
    f32x2 wfA[8], wfB[8];
#pragma unroll
    for (int q = 0; q < 8; ++q) {
        const float* wp = Wfc2 + q * 128 + u;
        wfA[q].x = wp[0]  * inv8;
        wfA[q].y = wp[32] * inv8;
        wfB[q].x = wp[64] * inv8;
        wfB[q].y = wp[96] * i8s3;
    }

    int nfirst = nbase + wv * 4;
    int beg = offs[nfirst];
#pragma unroll 1
    for (int j = 0; j < 4; ++j) {
        int end = offs[nfirst + j + 1];
        int cnt = end - beg;

        GAcc g;
        g.sa = 0.f; g.sb = 0.f; g.va2 = 0.f; g.vb2 = 0.f;
        g.va01 = (f32x2){0.f, 0.f};
        g.vb01 = (f32x2){0.f, 0.f};

        if (cnt > 0) {
            const char* recc = (const char*)rec;
            const char* xbc  = (const char*)xnode + u * 8;
            int T = (cnt + 1) >> 1;                  // wave-uniform trip count
            int cntH = (cnt + 1 - half) >> 1;        // this half's valid count
            int L = (end - 1) * 32;                  // last record byte offset
            int b0 = (beg + half) * 32;

            uint4 r00, r01, r10, r11, r20, r21, r30, r31, r40, r41, r50, r51;
            uint2 x0, x1, x2, x3, x4, x5;
            x4.x = 0u; x4.y = 0u; x5.x = 0u; x5.y = 0u;
            int p;
            p = min(b0,       L); r00 = *(const uint4*)(recc + p); r01 = *(const uint4*)(recc + p + 16);
            p = min(b0 + 64,  L); r10 = *(const uint4*)(recc + p); r11 = *(const uint4*)(recc + p + 16);
            p = min(b0 + 128, L); r20 = *(const uint4*)(recc + p); r21 = *(const uint4*)(recc + p + 16);
            p = min(b0 + 192, L); r30 = *(const uint4*)(recc + p); r31 = *(const uint4*)(recc + p + 16);
            p = min(b0 + 256, L); r40 = *(const uint4*)(recc + p); r41 = *(const uint4*)(recc + p + 16);
            p = min(b0 + 320, L); r50 = *(const uint4*)(recc + p); r51 = *(const uint4*)(recc + p + 16);
            int pf = min(b0 + 384, L);
            x0 = *(const uint2*)(xbc + r01.z);
            x1 = *(const uint2*)(xbc + r11.z);
            x2 = *(const uint2*)(xbc + r21.z);
            x3 = *(const uint2*)(xbc + r31.z);

            int t = 0;
            int Tm = T - 5;
            while (t < Tm) {   // 6 steps per pass; slots rotate by renaming
                gstep(r00, r01, x0, r41, x4, t, cntH, pf, L, recc, xbc, wfA, wfB, g);
                gstep(r10, r11, x1, r51, x5, t, cntH, pf, L, recc, xbc, wfA, wfB, g);
                gstep(r20, r21, x2, r01, x0, t, cntH, pf, L, recc, xbc, wfA, wfB, g);
                gstep(r30, r31, x3, r11, x1, t, cntH, pf, L, recc, xbc, wfA, wfB, g);
                gstep(r40, r41, x4, r21, x2, t, cntH, pf, L, recc, xbc, wfA, wfB, g);
                gstep(r50, r51, x5, r31, x3, t, cntH, pf, L, recc, xbc, wfA, wfB, g);
            }
            if (t < T) gstep(r00, r01, x0, r41, x4, t, cntH, pf, L, recc, xbc, wfA, wfB, g);
            if (t < T) gstep(r10, r11, x1, r51, x5, t, cntH, pf, L, recc, xbc, wfA, wfB, g);
            if (t < T) gstep(r20, r21, x2, r01, x0, t, cntH, pf, L, recc, xbc, wfA, wfB, g);
            if (t < T) gstep(r30, r31, x3, r11, x1, t, cntH, pf, L, recc, xbc, wfA, wfB, g);
            if (t < T) gstep(r40, r41, x4, r21, x2, t, cntH, pf, L, recc, xbc, wfA, wfB, g);
        }

        g.sa      += __shfl_xor(g.sa, 32, 64);
        g.sb      += __shfl_xor(g.sb, 32, 64);
        g.va01.x  += __shfl_xor(g.va01.x, 32, 64);
        g.va01.y  += __shfl_xor(g.va01.y, 32, 64);
        g.vb01.x  += __shfl_xor(g.vb01.x, 32, 64);
        g.vb01.y  += __shfl_xor(g.vb01.y, 32, 64);
        g.va2     += __shfl_xor(g.va2, 32, 64);
        g.vb2     += __shfl_xor(g.vb2, 32, 64);

        int nl = wv * 4 + j;
        unsigned short* ap = sAgg + nl * 264;
        if (half == 0) {
            ap[u]       = f2bf(g.sa);
            ap[32 + u]  = f2bf(g.sb);
            ap[64 + u]  = f2bf(g.va01.x);
            ap[96 + u]  = f2bf(g.vb01.x);
        } else {
            ap[128 + u] = f2bf(g.va01.y);
            ap[160 + u] = f2bf(g.vb01.y);
            ap[192 + u] = f2bf(g.va2);
            ap[224 + u] = f2bf(g.vb2);
        }
        beg = end;
    }
    __syncthreads();

    // ---- phase 2: MFMA output ----
    int col = lane & 15;
    int quad = lane >> 4;
    int m = col;
    bool is_s = (wv == 0);
    int sub = wv - 1;

    const short* Bs = (const short*)(is_s ? bsc0 : bsc1);
    const short* B2 = (const short*)(is_s ? b20 : b21);

    int aBase, fbase, fstep, n_a;
    if (is_s) {
        aBase = m * 264;
        fbase = m * 33;
        fstep = 1;
        n_a = nbase + m;
    } else {
        int r16 = 16 * sub + m;
        int nl = r16 / 3;
        int dd = r16 - nl * 3;
        aBase = nl * 264 + 64 + 64 * dd;
        fbase = nl * 100 + dd;
        fstep = 3;
        n_a = nbase + nl;
    }
    float4 A0 = *(const float4*)(node_attr + (size_t)n_a * 8);
    float4 A1 = *(const float4*)(node_attr + (size_t)n_a * 8 + 4);
    float aa0 = A0.x, aa1 = A0.y, aa2 = A0.z, aa3 = A0.w;
    float aa4 = A1.x, aa5 = A1.y, aa6 = A1.z, aa7 = A1.w;

    f32x4 acc0 = {0.f, 0.f, 0.f, 0.f};
    f32x4 acc1 = {0.f, 0.f, 0.f, 0.f};

#pragma unroll
    for (int kc = 0; kc < 2; ++kc) {
        short8 af = *(const short8*)((const short*)sAgg + aBase + kc * 32 + quad * 8);
        short8 bf0 = *(const short8*)(B2 + ((kc * 2 + 0) * 64 + lane) * 8);
        short8 bf1 = *(const short8*)(B2 + ((kc * 2 + 1) * 64 + lane) * 8);
        acc0 = __builtin_amdgcn_mfma_f32_16x16x32_bf16(af, bf0, acc0, 0, 0, 0);
        acc1 = __builtin_amdgcn_mfma_f32_16x16x32_bf16(af, bf1, acc1, 0, 0, 0);
    }
    const float* Sf = is_s ? sS : sV;
#pragma unroll
    for (int kc = 0; kc < 8; ++kc) {
        int uu = kc * 4 + quad;
        float f = Sf[fbase + uu * fstep];
        U8 af;
        af.u[0] = ptk(f * aa0, f * aa1);
        af.u[1] = ptk(f * aa2, f * aa3);
        af.u[2] = ptk(f * aa4, f * aa5);
        af.u[3] = ptk(f * aa6, f * aa7);
        short8 bf0 = *(const short8*)(Bs + ((kc * 2 + 0) * 64 + lane) * 8);
        short8 bf1 = *(const short8*)(Bs + ((kc * 2 + 1) * 64 + lane) * 8);
        acc0 = __builtin_amdgcn_mfma_f32_16x16x32_bf16(af.v, bf0, acc0, 0, 0, 0);
        acc1 = __builtin_amdgcn_mfma_f32_16x16x32_bf16(af.v, bf1, acc1, 0, 0, 0);
    }

    C4 c0, c1;
    c0.v = acc0; c1.v = acc1;
    if (is_s) {
#pragma unroll
        for (int r = 0; r < 4; ++r) {
            int n = nbase + (quad << 2) + r;
            out[(size_t)n * 128 + col]      = c0.f[r];
            out[(size_t)n * 128 + col + 16] = c1.f[r];
        }
    } else {
#pragma unroll
        for (int r = 0; r < 4; ++r) {
            int rl = 16 * sub + (quad << 2) + r;
            int nn = rl / 3;
            int dd = rl - nn * 3;
            int n = nbase + nn;
            out[(size_t)n * 128 + 32 + 3 * col + dd]        = c0.f[r];
            out[(size_t)n * 128 + 32 + 3 * (col + 16) + dd] = c1.f[r];
        }
    }
}

extern "C" void kernel_launch(void* const* d_in, const int* in_sizes, int n_in,
                              void* d_out, int out_size, void* d_ws, size_t ws_size,
                              hipStream_t stream) {
    const float* node_s       = (const float*)d_in[0];
    const float* node_v       = (const float*)d_in[1];
    const float* node_attr    = (const float*)d_in[2];
    const float* edge_attr    = (const float*)d_in[3];
    const float* edge_scalars = (const float*)d_in[4];
    const float* W1_0 = (const float*)d_in[5];
    const float* W1_1 = (const float*)d_in[6];
    const float* Wfc1 = (const float*)d_in[7];
    const float* Wfc2 = (const float*)d_in[8];
    const float* W2_0 = (const float*)d_in[9];
    const float* W2_1 = (const float*)d_in[10];
    const float* Wsc0 = (const float*)d_in[11];
    const float* Wsc1 = (const float*)d_in[12];
    const int* edge_src = (const int*)d_in[13];
    const int* edge_dst = (const int*)d_in[14];

    // workspace layout (bytes), total ~23.4MB
    char* ws = (char*)d_ws;
    unsigned short* xnode = (unsigned short*)(ws);              // N*128*2 = 7,680,000
    uint4* rec            = (uint4*)(ws + 7680000);             // E*32    = 15,360,000
    int* deg    = (int*)(ws + 23040000);                        // N*4
    int* offs   = (int*)(ws + 23160000);                        // (N+1)*4 pad
    unsigned* bsc0 = (unsigned*)(ws + 23400064);                // 16,384
    unsigned* bsc1 = (unsigned*)(ws + 23416448);                // 16,384
    unsigned* b20  = (unsigned*)(ws + 23432832);                // 4,096
    unsigned* b21  = (unsigned*)(ws + 23436928);                // 4,096

    // epos scratch lives in d_out (dead until k_main overwrites it)
    int* epos = (int*)d_out;

    hipMemsetAsync(deg, 0, (size_t)N_NODES * sizeof(int), stream);
    k_pre<<<1879, 256, 0, stream>>>(node_s, node_v, W1_0, W1_1, Wsc0, Wsc1,
                                    W2_0, W2_1, edge_src, deg, epos, xnode,
                                    bsc0, bsc1, b20, b21);
    scan_kernel<<<1, 1024, 0, stream>>>(deg, offs);
    fill_kernel<<<1875, 256, 0, stream>>>(edge_attr, edge_scalars, Wfc1,
                                          edge_src, edge_dst, offs, epos, rec);
    k_main<<<1875, 256, 0, stream>>>(offs, rec, Wfc2, xnode,
                                     node_s, node_v, node_attr,
                                     bsc0, bsc1, b20, b21, (float*)d_out);
}

// Round 14
// 214.724 us; speedup vs baseline: 1.0839x; 1.0839x over previous
//
#include <hip/hip_runtime.h>
#include <math.h>

#define N_NODES 30000
#define N_EDGES 480000

typedef __attribute__((ext_vector_type(8))) short short8;
typedef __attribute__((ext_vector_type(4))) float f32x4;
typedef __attribute__((ext_vector_type(2))) float f32x2;

__device__ __forceinline__ unsigned short f2bf(float f) {
    unsigned u = __float_as_uint(f);
    u += 0x7fff + ((u >> 16) & 1);          // RNE
    return (unsigned short)(u >> 16);
}
__device__ __forceinline__ float bfLO(unsigned v) { return __uint_as_float(v << 16); }
__device__ __forceinline__ float bfHI(unsigned v) { return __uint_as_float(v & 0xffff0000u); }
__device__ __forceinline__ unsigned packbf(float a, float b) {
    return (unsigned)f2bf(a) | ((unsigned)f2bf(b) << 16);
}
// truncation pack (products of bf16-exact values: err <= 2^-8, no carry chain)
__device__ __forceinline__ unsigned ptk(float a, float b) {
    return (__float_as_uint(a) >> 16) | (__float_as_uint(b) & 0xffff0000u);
}

union U8 { short8 v; unsigned u[4]; };
union C4 { f32x4 v; float f[4]; };

// ---------------------------------------------------------------------------
// k_pre: blocks 0..1874 (16 nodes each): x-precompute as MFMA GEMM, with the
// CSR degree count FUSED and the rank KEPT (epos[e] = old count) -- the
// atomic pass stays hidden under the GEMM (R3/R8-measured) while making fill
// atomic-free (R8: -14.5us vs cursor-atomic fill). epos lives in d_out
// (dead until k_main overwrites it). Blocks 1875..1878: pack W matrices.
// ---------------------------------------------------------------------------
__global__ __launch_bounds__(256) void k_pre(
    const float* __restrict__ node_s,   // (N,32)
    const float* __restrict__ node_v,   // (N,32,3)
    const float* __restrict__ W1_0,     // (32,32) [u][w]
    const float* __restrict__ W1_1,
    const float* __restrict__ Wsc0,     // (256,32)
    const float* __restrict__ Wsc1,
    const float* __restrict__ W2_0,     // (64,32)
    const float* __restrict__ W2_1,
    const int* __restrict__ edge_src,
    int* __restrict__ deg,
    int* __restrict__ epos,             // (E) CSR rank, in d_out
    unsigned short* __restrict__ xnode, // (N,128) bf16 packed
    unsigned* __restrict__ bsc0,        // 4096 uints
    unsigned* __restrict__ bsc1,
    unsigned* __restrict__ b20,         // 1024 uints
    unsigned* __restrict__ b21)
{
    __shared__ float sVT[16 * 100];     // [nl][d*32+u]
    __shared__ float sXo[16 * 140];     // [nl][p*34+w], p=0:x0, 1+d:x1_d
    int tid = threadIdx.x;

    if (blockIdx.x >= 1875) {
        int b = blockIdx.x - 1875;
        const float* Wm = (b == 0) ? Wsc0 : (b == 1) ? Wsc1 : (b == 2) ? W2_0 : W2_1;
        unsigned* dst = (b == 0) ? bsc0 : (b == 1) ? bsc1 : (b == 2) ? b20 : b21;
        float scale = (b < 2) ? 0.0625f : 0.03125f;  // exact pow2 folds
        int nu = (b < 2) ? 4096 : 1024;
        for (int idx = tid; idx < nu; idx += 256) {
            int jp = idx & 3;
            int lane = (idx >> 2) & 63;
            int ft = (idx >> 8) & 1;
            int kc = idx >> 9;
            int quad = lane >> 4, col = lane & 15;
            int k = kc * 32 + quad * 8 + jp * 2;
            int c = ft * 16 + col;
            dst[idx] = packbf(Wm[k * 32 + c] * scale, Wm[(k + 1) * 32 + c] * scale);
        }
        return;
    }

    int e = blockIdx.x * 256 + tid;
    epos[e] = atomicAdd(&deg[edge_src[e]], 1);   // hidden under GEMM below

    int nbase = blockIdx.x * 16;
    // stage node_v transposed: sVT[nl][d*32+u]
    for (int i = tid; i < 1536; i += 256) {
        int nl = i / 96, r = i - nl * 96;
        int u = r / 3, d = r - u * 3;
        sVT[nl * 100 + d * 32 + u] = node_v[(size_t)nbase * 96 + i];
    }
    __syncthreads();

    int lane = tid & 63;
    int wv = tid >> 6;
    int col = lane & 15, quad = lane >> 4, m = lane & 15;

    // B fragments from W1 (scale applied at pack stage)
    const float* W1 = (wv == 0) ? W1_0 : W1_1;
    U8 bf0, bf1;
#pragma unroll
    for (int p = 0; p < 4; ++p) {
        int k = quad * 8 + 2 * p;
        bf0.u[p] = packbf(W1[k * 32 + col],      W1[(k + 1) * 32 + col]);
        bf1.u[p] = packbf(W1[k * 32 + col + 16], W1[(k + 1) * 32 + col + 16]);
    }

    // A fragment (K=32 covered by one MFMA)
    U8 af;
    if (wv == 0) {
        const float* sp = node_s + (size_t)(nbase + m) * 32 + quad * 8;
        float4 a0 = *(const float4*)(sp);
        float4 a1 = *(const float4*)(sp + 4);
        af.u[0] = packbf(a0.x, a0.y); af.u[1] = packbf(a0.z, a0.w);
        af.u[2] = packbf(a1.x, a1.y); af.u[3] = packbf(a1.z, a1.w);
    } else {
        int R = 16 * (wv - 1) + m;
        int nl = R / 3, d = R - nl * 3;
        const float* vp = sVT + nl * 100 + d * 32 + quad * 8;
        af.u[0] = packbf(vp[0], vp[1]); af.u[1] = packbf(vp[2], vp[3]);
        af.u[2] = packbf(vp[4], vp[5]); af.u[3] = packbf(vp[6], vp[7]);
    }

    f32x4 acc0 = {0.f, 0.f, 0.f, 0.f};
    f32x4 acc1 = {0.f, 0.f, 0.f, 0.f};
    acc0 = __builtin_amdgcn_mfma_f32_16x16x32_bf16(af.v, bf0.v, acc0, 0, 0, 0);
    acc1 = __builtin_amdgcn_mfma_f32_16x16x32_bf16(af.v, bf1.v, acc1, 0, 0, 0);

    C4 c0, c1;
    c0.v = acc0; c1.v = acc1;
    if (wv == 0) {
#pragma unroll
        for (int r = 0; r < 4; ++r) {
            int nl = (quad << 2) + r;
            sXo[nl * 140 + col]      = c0.f[r];
            sXo[nl * 140 + col + 16] = c1.f[r];
        }
    } else {
#pragma unroll
        for (int r = 0; r < 4; ++r) {
            int R = 16 * (wv - 1) + (quad << 2) + r;
            int nl = R / 3, d = R - nl * 3;
            sXo[nl * 140 + (1 + d) * 34 + col]      = c0.f[r];
            sXo[nl * 140 + (1 + d) * 34 + col + 16] = c1.f[r];
        }
    }
    __syncthreads();

    const float inv_m = 0.1767766953f;  // 1/sqrt(32)
    for (int i = tid; i < 512; i += 256) {
        int nl = i >> 5, u = i & 31;
        const float* xp = sXo + nl * 140;
        uint2 pk;
        pk.x = packbf(xp[u] * inv_m,       xp[34 + u] * inv_m);
        pk.y = packbf(xp[68 + u] * inv_m,  xp[102 + u] * inv_m);
        *(uint2*)(xnode + (size_t)(nbase + nl) * 128 + u * 4) = pk;
    }
}

// ---------------------------------------------------------------------------
// scan: single-block exclusive prefix over deg -> offs (cursor no longer
// needed: fill is atomic-free).
// ---------------------------------------------------------------------------
__global__ __launch_bounds__(1024) void scan_kernel(const int* __restrict__ deg,
                                                    int* __restrict__ offs) {
    __shared__ int sdeg[N_NODES];
    __shared__ int wsum[16];
    int tid = threadIdx.x;
#pragma unroll
    for (int k = 0; k < 30; ++k) {
        int idx = k * 1024 + tid;
        if (idx < N_NODES) sdeg[idx] = deg[idx];
    }
    __syncthreads();
    int base = tid * 30;
    int s = 0;
    if (base < N_NODES) {
#pragma unroll
        for (int k = 0; k < 30; ++k) s += sdeg[base + k];
    }
    int lane = tid & 63, wid = tid >> 6;
    int inc = s;
#pragma unroll
    for (int d = 1; d < 64; d <<= 1) {
        int o = __shfl_up(inc, d, 64);
        if (lane >= d) inc += o;
    }
    if (lane == 63) wsum[wid] = inc;
    __syncthreads();
    if (tid < 16) {
        int v = wsum[tid];
        int t = v;
#pragma unroll
        for (int d = 1; d < 16; d <<= 1) {
            int o = __shfl_up(t, d, 64);
            if (tid >= d) t += o;
        }
        wsum[tid] = t - v;
    }
    __syncthreads();
    int run = inc - s + wsum[wid];
    if (base < N_NODES) {
#pragma unroll
        for (int k = 0; k < 30; ++k) {
            int n = base + k;
            int d = sdeg[n];
            sdeg[n] = run;
            run += d;
        }
    }
    __syncthreads();
#pragma unroll
    for (int k = 0; k < 30; ++k) {
        int idx = k * 1024 + tid;
        if (idx < N_NODES) offs[idx] = sdeg[idx];
    }
    if (tid == 0) offs[N_NODES] = N_EDGES;
}

// ---------------------------------------------------------------------------
// fill: per-edge radial MLP h = ssp(es@Wfc1/sqrt(8)); writes ONE 32B record
// per edge at its CSR slot: {h[8] bf16 | ea[4] bf16, dst*256 (byte off), pad}.
// ATOMIC-FREE: pos = offs[src] + epos[e] (rank saved by k_pre's hidden pass).
// Plain stores (R13 measured: nt stores evict rec from L2 and cost k_main
// +6.4us -- producer->consumer L2 residency beats RFO savings here).
// ---------------------------------------------------------------------------
__global__ __launch_bounds__(256) void fill_kernel(
    const float* __restrict__ edge_attr,     // (E,4)
    const float* __restrict__ edge_scalars,  // (E,8)
    const float* __restrict__ Wfc1,          // (8,8) [k][i]
    const int* __restrict__ edge_src,
    const int* __restrict__ edge_dst,
    const int* __restrict__ offs,
    const int* __restrict__ epos,
    uint4* __restrict__ rec)                 // (E,2) uint4
{
    __shared__ float sW[64];
    int tid = threadIdx.x;
    if (tid < 64) sW[tid] = Wfc1[tid];
    __syncthreads();

    int e = blockIdx.x * 256 + tid;
    float4 es0 = *(const float4*)(edge_scalars + (size_t)e * 8);
    float4 es1 = *(const float4*)(edge_scalars + (size_t)e * 8 + 4);
    float4 ea  = *(const float4*)(edge_attr + (size_t)e * 4);
    int src = edge_src[e];
    int dst = edge_dst[e];
    int pos = offs[src] + epos[e];

    const float inv8 = 0.3535533906f;
    float h[8];
#pragma unroll
    for (int i = 0; i < 8; ++i) {
        float acc = es0.x * sW[0 * 8 + i];
        acc = fmaf(es0.y, sW[1 * 8 + i], acc);
        acc = fmaf(es0.z, sW[2 * 8 + i], acc);
        acc = fmaf(es0.w, sW[3 * 8 + i], acc);
        acc = fmaf(es1.x, sW[4 * 8 + i], acc);
        acc = fmaf(es1.y, sW[5 * 8 + i], acc);
        acc = fmaf(es1.z, sW[6 * 8 + i], acc);
        acc = fmaf(es1.w, sW[7 * 8 + i], acc);
        acc *= inv8;
        float ax = fabsf(acc);
        float tt = __expf(-ax);
        h[i] = fmaxf(acc, 0.f) + __logf(1.f + tt) - 0.6931471806f;
    }
    uint4 r0, r1;
    r0.x = packbf(h[0], h[1]); r0.y = packbf(h[2], h[3]);
    r0.z = packbf(h[4], h[5]); r0.w = packbf(h[6], h[7]);
    r1.x = packbf(ea.x, ea.y); r1.y = packbf(ea.z, ea.w);
    r1.z = ((unsigned)dst) << 8;             // xnode BYTE offset
    r1.w = 0;
    rec[2 * pos]     = r0;
    rec[2 * pos + 1] = r1;
}

// ---------------------------------------------------------------------------
// k_main: FUSED gather + output GEMMs, 1875 blocks x 16 nodes (single
// dispatch: R6 proved half-grids collapse occupancy 45->28% VALUBusy).
// Phase 1: 4 waves x 4 sequential nodes; mov-free 6-slot rec pipeline,
//   x prefetched 4 steps ahead; Wfc2 direct from global (R5, -3us).
// Phase 2: W2 GEMM (K=64) + self-connection GEMM (K=256) via MFMA.
// ---------------------------------------------------------------------------
struct GAcc {
    float sa, sb, va2, vb2;
    f32x2 va01, vb01;
};

__device__ __forceinline__ void gstep(
    uint4& RS0, uint4& RS1, uint2& XS, const uint4& RN1, uint2& XN,
    int& t, int cntH, int& pf, int L,
    const char* recc, const char* xbc,
    const f32x2* wfA, const f32x2* wfB, GAcc& g)
{
    float hv[8];
    hv[0] = bfLO(RS0.x); hv[1] = bfHI(RS0.x);
    hv[2] = bfLO(RS0.y); hv[3] = bfHI(RS0.y);
    hv[4] = bfLO(RS0.z); hv[5] = bfHI(RS0.z);
    hv[6] = bfLO(RS0.w); hv[7] = bfHI(RS0.w);
    float sh0  = bfLO(RS1.x), s1xe = bfHI(RS1.x);
    float s1ye = bfLO(RS1.y), s1ze = bfHI(RS1.y);
    float xv0 = bfLO(XS.x), xd0 = bfHI(XS.x);
    float xd1 = bfLO(XS.y), xd2 = bfHI(XS.y);
    bool ok = (t < cntH);

    // prefetch rec[t+6] into the slot just consumed (clamped; harmless dup)
    RS0 = *(const uint4*)(recc + pf);
    RS1 = *(const uint4*)(recc + pf + 16);
    pf = min(pf + 64, L);
    // prefetch x[t+4] using rec[t+4]'s dst byte-offset
    XN = *(const uint2*)(xbc + RN1.z);

    f32x2 aA = {0.f, 0.f}, aB = {0.f, 0.f};
#pragma unroll
    for (int q = 0; q < 8; ++q) {
        f32x2 hh = {hv[q], hv[q]};
        aA = __builtin_elementwise_fma(hh, wfA[q], aA);
        aB = __builtin_elementwise_fma(hh, wfB[q], aB);
    }
    float a00 = ok ? aA.x : 0.f;
    float a01 = ok ? aA.y : 0.f;
    float a10 = ok ? aB.x : 0.f;
    float a11 = ok ? aB.y : 0.f;

    float dot = xd0 * s1xe + xd1 * s1ye + xd2 * s1ze;
    g.sa = fmaf(a00 * sh0, xv0, g.sa);
    g.sb = fmaf(a11, dot, g.sb);
    float w01x0 = a01 * xv0;
    float t10 = a10 * sh0;
    f32x2 wb = {w01x0, w01x0};
    f32x2 tb = {t10, t10};
    f32x2 s01 = {s1xe, s1ye};
    f32x2 xd01 = {xd0, xd1};
    g.va01 = __builtin_elementwise_fma(wb, s01, g.va01);
    g.vb01 = __builtin_elementwise_fma(tb, xd01, g.vb01);
    g.va2 = fmaf(w01x0, s1ze, g.va2);
    g.vb2 = fmaf(t10, xd2, g.vb2);
    ++t;
}

__global__ __launch_bounds__(256) void k_main(
    const int* __restrict__ offs,
    const uint4* __restrict__ rec,           // (E,2)
    const float* __restrict__ Wfc2,          // (8,128)
    const unsigned short* __restrict__ xnode,
    const float* __restrict__ node_s,        // (N,32)
    const float* __restrict__ node_v,        // (N,32,3)
    const float* __restrict__ node_attr,     // (N,8)
    const unsigned* __restrict__ bsc0,
    const unsigned* __restrict__ bsc1,
    const unsigned* __restrict__ b20,
    const unsigned* __restrict__ b21,
    float* __restrict__ out)                 // (N,128)
{
    __shared__ float sS[16 * 33];            // node_s staged [nl][u]
    __shared__ float sV[16 * 100];           // node_v staged [nl][u*3+d]
    __shared__ unsigned short sAgg[16 * 264];// agg rows [nl][ch], pad 8
    int tid = threadIdx.x;

    int nbase = blockIdx.x * 16;
    for (int i = tid; i < 512; i += 256)
        sS[(i >> 5) * 33 + (i & 31)] = node_s[(size_t)nbase * 32 + i];
    for (int i = tid; i < 1536; i += 256)
        sV[(i / 96) * 100 + (i % 96)] = node_v[(size_t)nbase * 96 + i];
    // no barrier needed: sS/sV first read after the phase-2 barrier

    int lane = tid & 63;
    int u = lane & 31;
    int half = lane >> 5;
    int wv = tid >> 6;

    // ---- phase 1: 4 sequential nodes per wave ----
    const float inv8 = 0.3535533906f;
    const float i8s3 = 0.3535533906f * 0.5773502692f;
    f32x2 wfA[8], wfB[8];
#pragma unroll
    for (int q = 0; q < 8; ++q) {
        const float* wp = Wfc2 + q * 128 + u;
        wfA[q].x = wp[0]  * inv8;
        wfA[q].y = wp[32] * inv8;
        wfB[q].x = wp[64] * inv8;
        wfB[q].y = wp[96] * i8s3;
    }

    int nfirst = nbase + wv * 4;
    int beg = offs[nfirst];
#pragma unroll 1
    for (int j = 0; j < 4; ++j) {
        int end = offs[nfirst + j + 1];
        int cnt = end - beg;

        GAcc g;
        g.sa = 0.f; g.sb = 0.f; g.va2 = 0.f; g.vb2 = 0.f;
        g.va01 = (f32x2){0.f, 0.f};
        g.vb01 = (f32x2){0.f, 0.f};

        if (cnt > 0) {
            const char* recc = (const char*)rec;
            const char* xbc  = (const char*)xnode + u * 8;
            int T = (cnt + 1) >> 1;                  // wave-uniform trip count
            int cntH = (cnt + 1 - half) >> 1;        // this half's valid count
            int L = (end - 1) * 32;                  // last record byte offset
            int b0 = (beg + half) * 32;

            uint4 r00, r01, r10, r11, r20, r21, r30, r31, r40, r41, r50, r51;
            uint2 x0, x1, x2, x3, x4, x5;
            x4.x = 0u; x4.y = 0u; x5.x = 0u; x5.y = 0u;
            int p;
            p = min(b0,       L); r00 = *(const uint4*)(recc + p); r01 = *(const uint4*)(recc + p + 16);
            p = min(b0 + 64,  L); r10 = *(const uint4*)(recc + p); r11 = *(const uint4*)(recc + p + 16);
            p = min(b0 + 128, L); r20 = *(const uint4*)(recc + p); r21 = *(const uint4*)(recc + p + 16);
            p = min(b0 + 192, L); r30 = *(const uint4*)(recc + p); r31 = *(const uint4*)(recc + p + 16);
            p = min(b0 + 256, L); r40 = *(const uint4*)(recc + p); r41 = *(const uint4*)(recc + p + 16);
            p = min(b0 + 320, L); r50 = *(const uint4*)(recc + p); r51 = *(const uint4*)(recc + p + 16);
            int pf = min(b0 + 384, L);
            x0 = *(const uint2*)(xbc + r01.z);
            x1 = *(const uint2*)(xbc + r11.z);
            x2 = *(const uint2*)(xbc + r21.z);
            x3 = *(const uint2*)(xbc + r31.z);

            int t = 0;
            int Tm = T - 5;
            while (t < Tm) {   // 6 steps per pass; slots rotate by renaming
                gstep(r00, r01, x0, r41, x4, t, cntH, pf, L, recc, xbc, wfA, wfB, g);
                gstep(r10, r11, x1, r51, x5, t, cntH, pf, L, recc, xbc, wfA, wfB, g);
                gstep(r20, r21, x2, r01, x0, t, cntH, pf, L, recc, xbc, wfA, wfB, g);
                gstep(r30, r31, x3, r11, x1, t, cntH, pf, L, recc, xbc, wfA, wfB, g);
                gstep(r40, r41, x4, r21, x2, t, cntH, pf, L, recc, xbc, wfA, wfB, g);
                gstep(r50, r51, x5, r31, x3, t, cntH, pf, L, recc, xbc, wfA, wfB, g);
            }
            if (t < T) gstep(r00, r01, x0, r41, x4, t, cntH, pf, L, recc, xbc, wfA, wfB, g);
            if (t < T) gstep(r10, r11, x1, r51, x5, t, cntH, pf, L, recc, xbc, wfA, wfB, g);
            if (t < T) gstep(r20, r21, x2, r01, x0, t, cntH, pf, L, recc, xbc, wfA, wfB, g);
            if (t < T) gstep(r30, r31, x3, r11, x1, t, cntH, pf, L, recc, xbc, wfA, wfB, g);
            if (t < T) gstep(r40, r41, x4, r21, x2, t, cntH, pf, L, recc, xbc, wfA, wfB, g);
        }

        g.sa      += __shfl_xor(g.sa, 32, 64);
        g.sb      += __shfl_xor(g.sb, 32, 64);
        g.va01.x  += __shfl_xor(g.va01.x, 32, 64);
        g.va01.y  += __shfl_xor(g.va01.y, 32, 64);
        g.vb01.x  += __shfl_xor(g.vb01.x, 32, 64);
        g.vb01.y  += __shfl_xor(g.vb01.y, 32, 64);
        g.va2     += __shfl_xor(g.va2, 32, 64);
        g.vb2     += __shfl_xor(g.vb2, 32, 64);

        int nl = wv * 4 + j;
        unsigned short* ap = sAgg + nl * 264;
        if (half == 0) {
            ap[u]       = f2bf(g.sa);
            ap[32 + u]  = f2bf(g.sb);
            ap[64 + u]  = f2bf(g.va01.x);
            ap[96 + u]  = f2bf(g.vb01.x);
        } else {
            ap[128 + u] = f2bf(g.va01.y);
            ap[160 + u] = f2bf(g.vb01.y);
            ap[192 + u] = f2bf(g.va2);
            ap[224 + u] = f2bf(g.vb2);
        }
        beg = end;
    }
    __syncthreads();

    // ---- phase 2: MFMA output ----
    int col = lane & 15;
    int quad = lane >> 4;
    int m = col;
    bool is_s = (wv == 0);
    int sub = wv - 1;

    const short* Bs = (const short*)(is_s ? bsc0 : bsc1);
    const short* B2 = (const short*)(is_s ? b20 : b21);

    int aBase, fbase, fstep, n_a;
    if (is_s) {
        aBase = m * 264;
        fbase = m * 33;
        fstep = 1;
        n_a = nbase + m;
    } else {
        int r16 = 16 * sub + m;
        int nl = r16 / 3;
        int dd = r16 - nl * 3;
        aBase = nl * 264 + 64 + 64 * dd;
        fbase = nl * 100 + dd;
        fstep = 3;
        n_a = nbase + nl;
    }
    float4 A0 = *(const float4*)(node_attr + (size_t)n_a * 8);
    float4 A1 = *(const float4*)(node_attr + (size_t)n_a * 8 + 4);
    float aa0 = A0.x, aa1 = A0.y, aa2 = A0.z, aa3 = A0.w;
    float aa4 = A1.x, aa5 = A1.y, aa6 = A1.z, aa7 = A1.w;

    f32x4 acc0 = {0.f, 0.f, 0.f, 0.f};
    f32x4 acc1 = {0.f, 0.f, 0.f, 0.f};

#pragma unroll
    for (int kc = 0; kc < 2; ++kc) {
        short8 af = *(const short8*)((const short*)sAgg + aBase + kc * 32 + quad * 8);
        short8 bf0 = *(const short8*)(B2 + ((kc * 2 + 0) * 64 + lane) * 8);
        short8 bf1 = *(const short8*)(B2 + ((kc * 2 + 1) * 64 + lane) * 8);
        acc0 = __builtin_amdgcn_mfma_f32_16x16x32_bf16(af, bf0, acc0, 0, 0, 0);
        acc1 = __builtin_amdgcn_mfma_f32_16x16x32_bf16(af, bf1, acc1, 0, 0, 0);
    }
    const float* Sf = is_s ? sS : sV;
#pragma unroll
    for (int kc = 0; kc < 8; ++kc) {
        int uu = kc * 4 + quad;
        float f = Sf[fbase + uu * fstep];
        U8 af;
        af.u[0] = ptk(f * aa0, f * aa1);
        af.u[1] = ptk(f * aa2, f * aa3);
        af.u[2] = ptk(f * aa4, f * aa5);
        af.u[3] = ptk(f * aa6, f * aa7);
        short8 bf0 = *(const short8*)(Bs + ((kc * 2 + 0) * 64 + lane) * 8);
        short8 bf1 = *(const short8*)(Bs + ((kc * 2 + 1) * 64 + lane) * 8);
        acc0 = __builtin_amdgcn_mfma_f32_16x16x32_bf16(af.v, bf0, acc0, 0, 0, 0);
        acc1 = __builtin_amdgcn_mfma_f32_16x16x32_bf16(af.v, bf1, acc1, 0, 0, 0);
    }

    C4 c0, c1;
    c0.v = acc0; c1.v = acc1;
    if (is_s) {
#pragma unroll
        for (int r = 0; r < 4; ++r) {
            int n = nbase + (quad << 2) + r;
            out[(size_t)n * 128 + col]      = c0.f[r];
            out[(size_t)n * 128 + col + 16] = c1.f[r];
        }
    } else {
#pragma unroll
        for (int r = 0; r < 4; ++r) {
            int rl = 16 * sub + (quad << 2) + r;
            int nn = rl / 3;
            int dd = rl - nn * 3;
            int n = nbase + nn;
            out[(size_t)n * 128 + 32 + 3 * col + dd]        = c0.f[r];
            out[(size_t)n * 128 + 32 + 3 * (col + 16) + dd] = c1.f[r];
        }
    }
}

extern "C" void kernel_launch(void* const* d_in, const int* in_sizes, int n_in,
                              void* d_out, int out_size, void* d_ws, size_t ws_size,
                              hipStream_t stream) {
    const float* node_s       = (const float*)d_in[0];
    const float* node_v       = (const float*)d_in[1];
    const float* node_attr    = (const float*)d_in[2];
    const float* edge_attr    = (const float*)d_in[3];
    const float* edge_scalars = (const float*)d_in[4];
    const float* W1_0 = (const float*)d_in[5];
    const float* W1_1 = (const float*)d_in[6];
    const float* Wfc1 = (const float*)d_in[7];
    const float* Wfc2 = (const float*)d_in[8];
    const float* W2_0 = (const float*)d_in[9];
    const float* W2_1 = (const float*)d_in[10];
    const float* Wsc0 = (const float*)d_in[11];
    const float* Wsc1 = (const float*)d_in[12];
    const int* edge_src = (const int*)d_in[13];
    const int* edge_dst = (const int*)d_in[14];

    // workspace layout (bytes), total ~23.4MB
    char* ws = (char*)d_ws;
    unsigned short* xnode = (unsigned short*)(ws);              // N*128*2 = 7,680,000
    uint4* rec            = (uint4*)(ws + 7680000);             // E*32    = 15,360,000
    int* deg    = (int*)(ws + 23040000);                        // N*4
    int* offs   = (int*)(ws + 23160000);                        // (N+1)*4 pad
    unsigned* bsc0 = (unsigned*)(ws + 23400064);                // 16,384
    unsigned* bsc1 = (unsigned*)(ws + 23416448);                // 16,384
    unsigned* b20  = (unsigned*)(ws + 23432832);                // 4,096
    unsigned* b21  = (unsigned*)(ws + 23436928);                // 4,096

    // epos scratch lives in d_out (dead until k_main overwrites it)
    int* epos = (int*)d_out;

    hipMemsetAsync(deg, 0, (size_t)N_NODES * sizeof(int), stream);
    k_pre<<<1879, 256, 0, stream>>>(node_s, node_v, W1_0, W1_1, Wsc0, Wsc1,
                                    W2_0, W2_1, edge_src, deg, epos, xnode,
                                    bsc0, bsc1, b20, b21);
    scan_kernel<<<1, 1024, 0, stream>>>(deg, offs);
    fill_kernel<<<1875, 256, 0, stream>>>(edge_attr, edge_scalars, Wfc1,
                                          edge_src, edge_dst, offs, epos, rec);
    k_main<<<1875, 256, 0, stream>>>(offs, rec, Wfc2, xnode,
                                     node_s, node_v, node_attr,
                                     bsc0, bsc1, b20, b21, (float*)d_out);
}